// Round 9
// baseline (330.341 us; speedup 1.0000x reference)
//
#include <hip/hip_runtime.h>
#include <stdint.h>
#include <cmath>

typedef short short8 __attribute__((ext_vector_type(8)));
typedef float f32x4 __attribute__((ext_vector_type(4)));

struct ResArr { float r[16]; };
struct DOff { int off[6]; };

__device__ __forceinline__ uint16_t f2bf(float f) {
  uint32_t u;
  __builtin_memcpy(&u, &f, 4);
  uint32_t r = (u + 0x7FFFu + ((u >> 16) & 1u)) >> 16;  // RNE
  return (uint16_t)r;
}

__device__ __forceinline__ uint32_t enc8(float v) {
  int q = __float2int_rn(v * 2048.0f);
  q = max(-127, min(127, q));
  return (uint32_t)(q & 0xFF);
}

// ---------------- prep: f32 table -> int8 pairs, hashed levels 6..15 -----
__global__ __launch_bounds__(256) void tbl_i8_kernel(
    const float4* __restrict__ t4, uint32_t* __restrict__ o, int n) {
  int i = blockIdx.x * 256 + threadIdx.x;
  int stride = gridDim.x * 256;
  for (; i < n; i += stride) {
    float4 v = t4[i];
    o[i] = enc8(v.x) | (enc8(v.y) << 8) | (enc8(v.z) << 16) | (enc8(v.w) << 24);
  }
}

// ---------------- prep: dense [x][z][y] tables for levels 0..5 -----------
// dword(x,z,y) = int8x4 (f0(z),f1(z),f0(z+1),f1(z+1)); y innermost so the 4
// (y,z)-corners of an x-slab sit in two adjacent dwords (~1 line/slab).
__global__ __launch_bounds__(256) void dense_build_kernel(
    const float* __restrict__ tablef, uint32_t* __restrict__ dt,
    DOff doffs, ResArr ra, int T) {
  int lvl = blockIdx.y;  // 0..5
  int r = (int)ra.r[lvl];
  int rp = r + 1;
  int n = rp * r * rp;  // x * z * y
  uint32_t mask = (uint32_t)(T - 1);
  const float* tb = tablef + (size_t)lvl * (size_t)T * 2;
  uint32_t* out = dt + doffs.off[lvl];
  for (int i = blockIdx.x * 256 + threadIdx.x; i < n; i += gridDim.x * 256) {
    int y = i % rp;
    int t = i / rp;
    int z = t % r;
    int x = t / r;
    uint32_t hxy = (uint32_t)x ^ (uint32_t)y * 2654435761u;
    uint32_t h0 = (hxy ^ (uint32_t)z * 805459861u) & mask;
    uint32_t h1 = (hxy ^ (uint32_t)(z + 1) * 805459861u) & mask;
    float a0 = tb[h0 * 2], a1 = tb[h0 * 2 + 1];
    float c0 = tb[h1 * 2], c1 = tb[h1 * 2 + 1];
    out[i] = enc8(a0) | (enc8(a1) << 8) | (enc8(c0) << 16) | (enc8(c1) << 24);
  }
}

// ---------------- prep: pack weights into MFMA B-fragment order (bf16) ----
__global__ __launch_bounds__(256) void prep_pack_kernel(
    const float* __restrict__ W1, const float* __restrict__ W2,
    const float* __restrict__ W3, uint16_t* __restrict__ pW1,
    uint16_t* __restrict__ pW2, uint16_t* __restrict__ pW3) {
  int i = blockIdx.x * 256 + threadIdx.x;
  if (i < 4096) {
    int j = i & 7, lane = (i >> 3) & 63, t = i >> 9;
    int k = (lane >> 4) * 8 + j, col = t * 16 + (lane & 15);
    pW1[i] = f2bf(W1[k * 128 + col]);
  } else if (i < 20480) {
    int q = i - 4096;
    int j = q & 7, lane = (q >> 3) & 63, st = q >> 9;
    int s = st & 3, t = st >> 2;
    int k = s * 32 + (lane >> 4) * 8 + j, col = t * 16 + (lane & 15);
    pW2[q] = f2bf(W2[k * 128 + col]);
  } else if (i < 26624) {
    int q = i - 20480;
    int j = q & 7, lane = (q >> 3) & 63, st = q >> 9;
    int s = st & 3, t = st >> 2;
    int k = s * 32 + (lane >> 4) * 8 + j, col = t * 16 + (lane & 15);
    pW3[q] = (col < 42) ? f2bf(W3[k * 42 + col]) : (uint16_t)0;
  }
}

// b1' = b1 + cond @ W1[32:160]
__global__ void prep_b1p_kernel(const float* __restrict__ b1,
                                const float* __restrict__ cond,
                                const float* __restrict__ W1,
                                float* __restrict__ b1p) {
  int j = threadIdx.x;  // 128 threads
  float acc = b1[j];
  for (int c = 0; c < 128; ++c) acc += cond[c] * W1[(32 + c) * 128 + j];
  b1p[j] = acc;
}

// ---------------- FUSED hash-encode + MLP + epilogue ---------------------
// Block = 256 thr = 64 points. Phase 1: thread (pt=tid&63, grp=tid>>6)
// computes 4 levels -> feat LDS. Phase 2: 4 waves x 16 pts MFMA MLP.
// Blocks at different phases co-schedule per CU: MLP's MFMA/VALU fills the
// hash phase's gather-latency stalls (pipes are independent, m114).
__global__ __launch_bounds__(256) void fused_kernel(
    const float* __restrict__ xyz, const float* __restrict__ amin,
    const float* __restrict__ amax, const uint32_t* __restrict__ tbl8,
    const uint32_t* __restrict__ dtbl, const uint16_t* __restrict__ pW1,
    const uint16_t* __restrict__ pW2, const uint16_t* __restrict__ pW3,
    const float* __restrict__ b1p, const float* __restrict__ b2,
    const float* __restrict__ b3, const float* __restrict__ scal,
    const float* __restrict__ rot, float* __restrict__ out,
    float* __restrict__ partial, int N, int T, ResArr ra, DOff doffs) {
  __shared__ uint32_t feat_lds[16][64];
  __shared__ float xyz_s[192];
  __shared__ alignas(16) uint16_t h_lds[4 * 16 * 136];  // reused L1->L2 out
  __shared__ float dd[4][16][12];
  __shared__ float bl[4][3];

  int tid = threadIdx.x;
  int pbase = blockIdx.x * 64;

  // coalesced xyz stage (64 pts * 3)
  if (tid < 192) {
    int gidx = pbase * 3 + tid;
    xyz_s[tid] = xyz[min(gidx, N * 3 - 1)];
  }
  __syncthreads();

  // ================= phase 1: hash encode (4 levels / thread) ============
  {
    int ptl = tid & 63, grp = tid >> 6;
    int lc = min(pbase + ptl, N - 1) - pbase;
    float mn0 = amin[0], mn1 = amin[1], mn2 = amin[2];
    float x = (xyz_s[lc * 3 + 0] - mn0) / (amax[0] - mn0);
    float y = (xyz_s[lc * 3 + 1] - mn1) / (amax[1] - mn1);
    float z = (xyz_s[lc * 3 + 2] - mn2) / (amax[2] - mn2);
    const float hi = 1.0f - 1e-6f;
    x = fminf(fmaxf(x, 0.f), hi);
    y = fminf(fmaxf(y, 0.f), hi);
    z = fminf(fmaxf(z, 0.f), hi);
    uint32_t mask = (uint32_t)(T - 1);
    const float s = 1.0f / 2048.0f;

#pragma unroll
    for (int q = 0; q < 4; ++q) {
      int lvl = grp * 4 + q;
      float res = ra.r[lvl];
      float xs0 = x * res, xs1 = y * res, xs2 = z * res;
      float c0 = floorf(xs0), c1 = floorf(xs1), c2 = floorf(xs2);
      float fr0 = xs0 - c0, fr1 = xs1 - c1, fr2 = xs2 - c2;
      int j0 = (int)c0, j1 = (int)c1, j2 = (int)c2;
      float wy0 = 1.f - fr1, wz0 = 1.f - fr2;
      float acc0 = 0.f, acc1 = 0.f;

      if (lvl < 6) {
        int r = (int)res, rp = r + 1;
        const uint32_t* dtb = dtbl + doffs.off[lvl];
#pragma unroll
        for (int bx = 0; bx < 2; ++bx) {
          int base = ((j0 + bx) * r + j2) * rp + j1;
          uint32_t u0 = dtb[base];
          uint32_t u1 = dtb[base + 1];
          float a0 = (float)((int)(u0 << 24) >> 24);
          float a1 = (float)((int)(u0 << 16) >> 24);
          float a2 = (float)((int)(u0 << 8) >> 24);
          float a3 = (float)((int)u0 >> 24);
          float b0 = (float)((int)(u1 << 24) >> 24);
          float b1v = (float)((int)(u1 << 16) >> 24);
          float b2v = (float)((int)(u1 << 8) >> 24);
          float b3v = (float)((int)u1 >> 24);
          float gy0_0 = a0 + fr2 * (a2 - a0), gy0_1 = a1 + fr2 * (a3 - a1);
          float gy1_0 = b0 + fr2 * (b2v - b0), gy1_1 = b1v + fr2 * (b3v - b1v);
          float h0 = gy0_0 + fr1 * (gy1_0 - gy0_0);
          float h1v = gy0_1 + fr1 * (gy1_1 - gy0_1);
          float wx = bx ? fr0 : (1.f - fr0);
          acc0 += wx * h0;
          acc1 += wx * h1v;
        }
      } else {
        uint32_t j0u = (uint32_t)j0;
        const uint32_t* tb = tbl8 + (size_t)(lvl - 6) * (size_t)(T >> 1);
        uint32_t hy0 = (uint32_t)j1 * 2654435761u, hy1 = hy0 + 2654435761u;
        uint32_t hz0 = (uint32_t)j2 * 805459861u, hz1 = hz0 + 805459861u;
        bool odd = (j0u & 1u) != 0u;
#pragma unroll
        for (int c = 0; c < 4; ++c) {
          uint32_t hyz = ((c & 1) ? hy1 : hy0) ^ ((c >> 1) ? hz1 : hz0);
          uint32_t idx0 = (j0u ^ hyz) & mask;
          uint32_t idx1 = ((j0u + 1u) ^ hyz) & mask;
          uint32_t u = tb[idx0 >> 1];
          uint32_t u2 = u;
          if (odd) u2 = tb[idx1 >> 1];
          uint32_t ha = (idx0 & 1u) ? (u >> 16) : (u & 0xFFFFu);
          uint32_t hb = (idx1 & 1u) ? (u2 >> 16) : (u2 & 0xFFFFu);
          float fa0 = (float)((int)(ha << 24) >> 24);
          float fa1 = (float)((int)(ha << 16) >> 24);
          float fb0 = (float)((int)(hb << 24) >> 24);
          float fb1 = (float)((int)(hb << 16) >> 24);
          float g0 = fa0 + fr0 * (fb0 - fa0);
          float g1 = fa1 + fr0 * (fb1 - fa1);
          float wyz = ((c & 1) ? fr1 : wy0) * ((c >> 1) ? fr2 : wz0);
          acc0 += wyz * g0;
          acc1 += wyz * g1;
        }
      }
      feat_lds[lvl][ptl] =
          (uint32_t)f2bf(acc0 * s) | ((uint32_t)f2bf(acc1 * s) << 16);
    }
  }
  __syncthreads();

  // ================= phase 2: MFMA MLP ===================================
  int wv = tid >> 6, lane = tid & 63;
  int rowi = lane & 15, g = lane >> 4;
  int pb_w = pbase + wv * 16;
  int lrow = min(wv * 16 + rowi, N - 1 - pbase);

  union { uint32_t u[4]; short8 v; } cva;
#pragma unroll
  for (int jj = 0; jj < 4; ++jj)
    cva.u[jj] = feat_lds[g * 4 + jj][lrow];
  short8 a1 = cva.v;

  uint16_t* hw = &h_lds[wv * 16 * 136];
  const short8* w1f = (const short8*)pW1;
#pragma unroll
  for (int t = 0; t < 8; ++t) {
    float bb = b1p[t * 16 + rowi];
    f32x4 c = {bb, bb, bb, bb};
    c = __builtin_amdgcn_mfma_f32_16x16x32_bf16(a1, w1f[t * 64 + lane], c, 0, 0, 0);
#pragma unroll
    for (int r = 0; r < 4; ++r)
      hw[(4 * g + r) * 136 + t * 16 + rowi] = f2bf(fmaxf(c[r], 0.f));
  }

  // layer 2 (reads h then overwrites same per-wave slice; DS in-order/wave)
  short8 a2[4];
#pragma unroll
  for (int s = 0; s < 4; ++s)
    a2[s] = *(const short8*)&hw[rowi * 136 + s * 32 + g * 8];
  const short8* w2f = (const short8*)pW2;
#pragma unroll
  for (int t = 0; t < 8; ++t) {
    float bb = b2[t * 16 + rowi];
    f32x4 c = {bb, bb, bb, bb};
#pragma unroll
    for (int s = 0; s < 4; ++s)
      c = __builtin_amdgcn_mfma_f32_16x16x32_bf16(a2[s], w2f[(t * 4 + s) * 64 + lane], c, 0, 0, 0);
#pragma unroll
    for (int r = 0; r < 4; ++r)
      hw[(4 * g + r) * 136 + t * 16 + rowi] = f2bf(fmaxf(c[r], 0.f));
  }

  // layer 3
  short8 a3[4];
#pragma unroll
  for (int s = 0; s < 4; ++s)
    a3[s] = *(const short8*)&hw[rowi * 136 + s * 32 + g * 8];
  const short8* w3f = (const short8*)pW3;
#pragma unroll
  for (int t = 0; t < 3; ++t) {
    int col = t * 16 + rowi;
    float bb = (col < 42) ? b3[col] : 0.f;
    f32x4 c = {bb, bb, bb, bb};
#pragma unroll
    for (int s = 0; s < 4; ++s)
      c = __builtin_amdgcn_mfma_f32_16x16x32_bf16(a3[s], w3f[(t * 4 + s) * 64 + lane], c, 0, 0, 0);
    if (col >= 10 && col < 42) {
#pragma unroll
      for (int r = 0; r < 4; ++r) {
        int p = pb_w + 4 * g + r;
        if (p < N) out[(size_t)p * 42 + col] = c[r];
      }
    } else if (col < 10) {
#pragma unroll
      for (int r = 0; r < 4; ++r) dd[wv][4 * g + r][col] = c[r];
    }
  }

  // epilogue (per-wave; dd is per-wave so only in-wave ordering needed)
  float lx = 0.f, ls = 0.f, lr = 0.f;
  if (lane < 16) {
    int p = pb_w + lane;
    if (p < N) {
      float d0 = dd[wv][lane][0], d1 = dd[wv][lane][1], d2 = dd[wv][lane][2];
      float d3 = dd[wv][lane][3], d4 = dd[wv][lane][4], d5 = dd[wv][lane][5];
      float d6 = dd[wv][lane][6], d7 = dd[wv][lane][7], d8 = dd[wv][lane][8];
      float d9 = dd[wv][lane][9];
      size_t ob = (size_t)p * 42;
      out[ob + 0] = xyz[p * 3 + 0] + d0;
      out[ob + 1] = xyz[p * 3 + 1] + d1;
      out[ob + 2] = xyz[p * 3 + 2] + d2;
      out[ob + 3] = scal[p * 3 + 0] + d3;
      out[ob + 4] = scal[p * 3 + 1] + d4;
      out[ob + 5] = scal[p * 3 + 2] + d5;
      out[ob + 6] = rot[p * 4 + 0] + d6;
      out[ob + 7] = rot[p * 4 + 1] + d7;
      out[ob + 8] = rot[p * 4 + 2] + d8;
      out[ob + 9] = rot[p * 4 + 3] + d9;
      lx = sqrtf(d0 * d0 + d1 * d1 + d2 * d2);
      ls = fabsf(d3) + fabsf(d4) + fabsf(d5);
      lr = fabsf(d6) + fabsf(d7) + fabsf(d8) + fabsf(d9);
    }
  }
#pragma unroll
  for (int off = 32; off; off >>= 1) {
    lx += __shfl_xor(lx, off);
    ls += __shfl_xor(ls, off);
    lr += __shfl_xor(lr, off);
  }
  if (lane == 0) { bl[wv][0] = lx; bl[wv][1] = ls; bl[wv][2] = lr; }
  __syncthreads();
  if (tid == 0) {
    partial[(size_t)blockIdx.x * 3 + 0] = bl[0][0] + bl[1][0] + bl[2][0] + bl[3][0];
    partial[(size_t)blockIdx.x * 3 + 1] = bl[0][1] + bl[1][1] + bl[2][1] + bl[3][1];
    partial[(size_t)blockIdx.x * 3 + 2] = bl[0][2] + bl[1][2] + bl[2][2] + bl[3][2];
  }
}

// ---------------- finalize: losses row N ---------------------------------
__global__ void finalize_kernel(const float* __restrict__ partial, int nb,
                                float* __restrict__ out, int N) {
  int tid = threadIdx.x, wv = tid >> 6, lane = tid & 63;
  __shared__ float red[4][3];
  float s0 = 0.f, s1 = 0.f, s2 = 0.f;
  for (int i = tid; i < nb; i += 256) {
    s0 += partial[(size_t)i * 3 + 0];
    s1 += partial[(size_t)i * 3 + 1];
    s2 += partial[(size_t)i * 3 + 2];
  }
#pragma unroll
  for (int off = 32; off; off >>= 1) {
    s0 += __shfl_xor(s0, off);
    s1 += __shfl_xor(s1, off);
    s2 += __shfl_xor(s2, off);
  }
  if (lane == 0) { red[wv][0] = s0; red[wv][1] = s1; red[wv][2] = s2; }
  __syncthreads();
  size_t base = (size_t)N * 42;
  if (tid == 0) {
    float t0 = red[0][0] + red[1][0] + red[2][0] + red[3][0];
    float t1 = red[0][1] + red[1][1] + red[2][1] + red[3][1];
    float t2 = red[0][2] + red[1][2] + red[2][2] + red[3][2];
    out[base + 0] = t0 / (float)N;
    out[base + 1] = t1 / (float)N;
    out[base + 2] = t2 / (float)N;
  }
  if (tid >= 3 && tid < 42) out[base + tid] = 0.f;
}

extern "C" void kernel_launch(void* const* d_in, const int* in_sizes, int n_in,
                              void* d_out, int out_size, void* d_ws,
                              size_t ws_size, hipStream_t stream) {
  const float* xyz = (const float*)d_in[0];
  const float* scal = (const float*)d_in[1];
  const float* rot = (const float*)d_in[2];
  const float* cond = (const float*)d_in[3];
  const float* table = (const float*)d_in[4];
  const float* amin = (const float*)d_in[5];
  const float* amax = (const float*)d_in[6];
  const float* W1 = (const float*)d_in[7];
  const float* b1 = (const float*)d_in[8];
  const float* W2 = (const float*)d_in[9];
  const float* b2 = (const float*)d_in[10];
  const float* W3 = (const float*)d_in[11];
  const float* b3 = (const float*)d_in[12];
  float* out = (float*)d_out;

  int N = in_sizes[0] / 3;
  int T = in_sizes[4] / (16 * 2);
  int nb = (N + 63) / 64;

  ResArr ra;
  double growth = std::pow(2048.0 / 16.0, 1.0 / 15.0);
  for (int l = 0; l < 16; ++l)
    ra.r[l] = (float)std::floor(16.0 * std::pow(growth, (double)l));

  DOff doffs;
  int doff = 0;
  int dmaxn = 0;
  for (int l = 0; l < 6; ++l) {
    doffs.off[l] = doff;
    int r = (int)ra.r[l];
    int n = (r + 1) * r * (r + 1);
    if (n > dmaxn) dmaxn = n;
    doff += n;
  }

  char* ws = (char*)d_ws;
  size_t off = 0;
  uint16_t* pW1 = (uint16_t*)(ws + off); off += 4096 * 2;
  uint16_t* pW2 = (uint16_t*)(ws + off); off += 16384 * 2;
  uint16_t* pW3 = (uint16_t*)(ws + off); off += 6144 * 2;
  float* b1p = (float*)(ws + off); off += 128 * 4;
  float* partial = (float*)(ws + off); off += (size_t)nb * 3 * 4;
  off = (off + 15) & ~(size_t)15;
  uint32_t* tbl8 = (uint32_t*)(ws + off); off += (size_t)10 * (size_t)(T >> 1) * 4;
  uint32_t* dtbl = (uint32_t*)(ws + off); off += (size_t)doff * 4;

  prep_pack_kernel<<<104, 256, 0, stream>>>(W1, W2, W3, pW1, pW2, pW3);
  prep_b1p_kernel<<<1, 128, 0, stream>>>(b1, cond, W1, b1p);

  int n_i8 = 10 * (T >> 1);
  const float4* t4base = (const float4*)(table + (size_t)6 * (size_t)T * 2);
  tbl_i8_kernel<<<2048, 256, 0, stream>>>(t4base, tbl8, n_i8);
  dense_build_kernel<<<dim3((dmaxn + 255) / 256, 6), 256, 0, stream>>>(
      table, dtbl, doffs, ra, T);

  fused_kernel<<<nb, 256, 0, stream>>>(xyz, amin, amax, tbl8, dtbl, pW1, pW2,
                                       pW3, b1p, b2, b3, scal, rot, out,
                                       partial, N, T, ra, doffs);
  finalize_kernel<<<1, 256, 0, stream>>>(partial, nb, out, N);
}

// Round 10
// 271.564 us; speedup vs baseline: 1.2164x; 1.2164x over previous
//
#include <hip/hip_runtime.h>
#include <stdint.h>
#include <cmath>

typedef short short8 __attribute__((ext_vector_type(8)));
typedef float f32x4 __attribute__((ext_vector_type(4)));

struct ResArr { float r[16]; };
struct DOff { int off[6]; };

__device__ __forceinline__ uint16_t f2bf(float f) {
  uint32_t u;
  __builtin_memcpy(&u, &f, 4);
  uint32_t r = (u + 0x7FFFu + ((u >> 16) & 1u)) >> 16;  // RNE
  return (uint16_t)r;
}

// pack two f32 -> dword of 2 bf16 (round-to-nearest, ties away; margin ok)
__device__ __forceinline__ uint32_t pack_bf2(float lo, float hi) {
  uint32_t ul, uh;
  __builtin_memcpy(&ul, &lo, 4);
  __builtin_memcpy(&uh, &hi, 4);
  return ((ul + 0x8000u) >> 16) | ((uh + 0x8000u) & 0xFFFF0000u);
}

__device__ __forceinline__ uint32_t enc8(float v) {
  int q = __float2int_rn(v * 2048.0f);
  q = max(-127, min(127, q));
  return (uint32_t)(q & 0xFF);
}

// ---------------- prep: f32 table -> int8 pairs, hashed levels 6..15 -----
__global__ __launch_bounds__(256) void tbl_i8_kernel(
    const float4* __restrict__ t4, uint32_t* __restrict__ o, int n) {
  int i = blockIdx.x * 256 + threadIdx.x;
  int stride = gridDim.x * 256;
  for (; i < n; i += stride) {
    float4 v = t4[i];
    o[i] = enc8(v.x) | (enc8(v.y) << 8) | (enc8(v.z) << 16) | (enc8(v.w) << 24);
  }
}

// ---------------- prep: dense [x][z][y] tables for levels 0..5 -----------
__global__ __launch_bounds__(256) void dense_build_kernel(
    const float* __restrict__ tablef, uint32_t* __restrict__ dt,
    DOff doffs, ResArr ra, int T) {
  int lvl = blockIdx.y;  // 0..5
  int r = (int)ra.r[lvl];
  int rp = r + 1;
  int n = rp * r * rp;  // x * z * y
  uint32_t mask = (uint32_t)(T - 1);
  const float* tb = tablef + (size_t)lvl * (size_t)T * 2;
  uint32_t* out = dt + doffs.off[lvl];
  for (int i = blockIdx.x * 256 + threadIdx.x; i < n; i += gridDim.x * 256) {
    int y = i % rp;
    int t = i / rp;
    int z = t % r;
    int x = t / r;
    uint32_t hxy = (uint32_t)x ^ (uint32_t)y * 2654435761u;
    uint32_t h0 = (hxy ^ (uint32_t)z * 805459861u) & mask;
    uint32_t h1 = (hxy ^ (uint32_t)(z + 1) * 805459861u) & mask;
    float a0 = tb[h0 * 2], a1 = tb[h0 * 2 + 1];
    float c0 = tb[h1 * 2], c1 = tb[h1 * 2 + 1];
    out[i] = enc8(a0) | (enc8(a1) << 8) | (enc8(c0) << 16) | (enc8(c1) << 24);
  }
}

// ---------------- prep: pack weights into MFMA fragment order (bf16) -----
// Layout is self-dual: element [(t*nS+s)*64+lane]*? holds W[k][t*16+(lane&15)]
// with k = s*32 + (lane>>4)*8 + j  -- valid as B(col=lane&15) AND as
// A(row=lane&15) of W^T. Unchanged from prior rounds.
__global__ __launch_bounds__(256) void prep_pack_kernel(
    const float* __restrict__ W1, const float* __restrict__ W2,
    const float* __restrict__ W3, uint16_t* __restrict__ pW1,
    uint16_t* __restrict__ pW2, uint16_t* __restrict__ pW3) {
  int i = blockIdx.x * 256 + threadIdx.x;
  if (i < 4096) {
    int j = i & 7, lane = (i >> 3) & 63, t = i >> 9;
    int k = (lane >> 4) * 8 + j, col = t * 16 + (lane & 15);
    pW1[i] = f2bf(W1[k * 128 + col]);
  } else if (i < 20480) {
    int q = i - 4096;
    int j = q & 7, lane = (q >> 3) & 63, st = q >> 9;
    int s = st & 3, t = st >> 2;
    int k = s * 32 + (lane >> 4) * 8 + j, col = t * 16 + (lane & 15);
    pW2[q] = f2bf(W2[k * 128 + col]);
  } else if (i < 26624) {
    int q = i - 20480;
    int j = q & 7, lane = (q >> 3) & 63, st = q >> 9;
    int s = st & 3, t = st >> 2;
    int k = s * 32 + (lane >> 4) * 8 + j, col = t * 16 + (lane & 15);
    pW3[q] = (col < 42) ? f2bf(W3[k * 42 + col]) : (uint16_t)0;
  }
}

// b1' = b1 + cond @ W1[32:160]; also b3 padded to 48 (b3p)
__global__ void prep_b1p_kernel(const float* __restrict__ b1,
                                const float* __restrict__ cond,
                                const float* __restrict__ W1,
                                const float* __restrict__ b3,
                                float* __restrict__ b1p,
                                float* __restrict__ b3p) {
  int j = threadIdx.x;  // 192 threads
  if (j < 128) {
    float acc = b1[j];
    for (int c = 0; c < 128; ++c) acc += cond[c] * W1[(32 + c) * 128 + j];
    b1p[j] = acc;
  } else if (j < 176) {
    int k = j - 128;
    b3p[k] = (k < 42) ? b3[k] : 0.f;
  }
}

// ---------------- hash grid encode v8 (unchanged, session-best) ----------
__global__ __launch_bounds__(256) void hash_enc8_kernel(
    const float* __restrict__ xyz, const float* __restrict__ amin,
    const float* __restrict__ amax, const uint32_t* __restrict__ tbl8,
    const uint32_t* __restrict__ dtbl, uint32_t* __restrict__ featw,
    int N, int T, ResArr ra, DOff doffs) {
  int lvl = blockIdx.y;
  int p = blockIdx.x * 256 + threadIdx.x;
  if (p >= N) return;

  float mn0 = amin[0], mn1 = amin[1], mn2 = amin[2];
  float x = (xyz[p * 3 + 0] - mn0) / (amax[0] - mn0);
  float y = (xyz[p * 3 + 1] - mn1) / (amax[1] - mn1);
  float z = (xyz[p * 3 + 2] - mn2) / (amax[2] - mn2);
  const float hi = 1.0f - 1e-6f;
  x = fminf(fmaxf(x, 0.f), hi);
  y = fminf(fmaxf(y, 0.f), hi);
  z = fminf(fmaxf(z, 0.f), hi);

  float res = ra.r[lvl];
  float xs0 = x * res, xs1 = y * res, xs2 = z * res;
  float c0 = floorf(xs0), c1 = floorf(xs1), c2 = floorf(xs2);
  float fr0 = xs0 - c0, fr1 = xs1 - c1, fr2 = xs2 - c2;
  int j0 = (int)c0, j1 = (int)c1, j2 = (int)c2;

  float wy0 = 1.f - fr1, wz0 = 1.f - fr2;
  float acc0 = 0.f, acc1 = 0.f;

  if (lvl < 6) {
    int r = (int)res, rp = r + 1;
    const uint32_t* dtb = dtbl + doffs.off[lvl];
#pragma unroll
    for (int bx = 0; bx < 2; ++bx) {
      int base = ((j0 + bx) * r + j2) * rp + j1;
      uint32_t u0 = dtb[base];
      uint32_t u1 = dtb[base + 1];
      float a0 = (float)((int)(u0 << 24) >> 24);
      float a1 = (float)((int)(u0 << 16) >> 24);
      float a2 = (float)((int)(u0 << 8) >> 24);
      float a3 = (float)((int)u0 >> 24);
      float b0 = (float)((int)(u1 << 24) >> 24);
      float b1v = (float)((int)(u1 << 16) >> 24);
      float b2 = (float)((int)(u1 << 8) >> 24);
      float b3 = (float)((int)u1 >> 24);
      float gy0_0 = a0 + fr2 * (a2 - a0), gy0_1 = a1 + fr2 * (a3 - a1);
      float gy1_0 = b0 + fr2 * (b2 - b0), gy1_1 = b1v + fr2 * (b3 - b1v);
      float h0 = gy0_0 + fr1 * (gy1_0 - gy0_0);
      float h1v = gy0_1 + fr1 * (gy1_1 - gy0_1);
      float wx = bx ? fr0 : (1.f - fr0);
      acc0 += wx * h0;
      acc1 += wx * h1v;
    }
  } else {
    uint32_t j0u = (uint32_t)j0;
    uint32_t mask = (uint32_t)(T - 1);
    const uint32_t* tb = tbl8 + (size_t)(lvl - 6) * (size_t)(T >> 1);
    uint32_t hy0 = (uint32_t)j1 * 2654435761u, hy1 = hy0 + 2654435761u;
    uint32_t hz0 = (uint32_t)j2 * 805459861u, hz1 = hz0 + 805459861u;
    bool odd = (j0u & 1u) != 0u;
#pragma unroll
    for (int c = 0; c < 4; ++c) {
      uint32_t hyz = ((c & 1) ? hy1 : hy0) ^ ((c >> 1) ? hz1 : hz0);
      uint32_t idx0 = (j0u ^ hyz) & mask;
      uint32_t idx1 = ((j0u + 1u) ^ hyz) & mask;
      uint32_t u = tb[idx0 >> 1];
      uint32_t u2 = u;
      if (odd) u2 = tb[idx1 >> 1];
      uint32_t ha = (idx0 & 1u) ? (u >> 16) : (u & 0xFFFFu);
      uint32_t hb = (idx1 & 1u) ? (u2 >> 16) : (u2 & 0xFFFFu);
      float fa0 = (float)((int)(ha << 24) >> 24);
      float fa1 = (float)((int)(ha << 16) >> 24);
      float fb0 = (float)((int)(hb << 24) >> 24);
      float fb1 = (float)((int)(hb << 16) >> 24);
      float g0 = fa0 + fr0 * (fb0 - fa0);
      float g1 = fa1 + fr0 * (fb1 - fa1);
      float wyz = ((c & 1) ? fr1 : wy0) * ((c >> 1) ? fr2 : wz0);
      acc0 += wyz * g0;
      acc1 += wyz * g1;
    }
  }

  const float s = 1.0f / 2048.0f;
  featw[(size_t)lvl * N + p] =
      (uint32_t)f2bf(acc0 * s) | ((uint32_t)f2bf(acc1 * s) << 16);
}

// ---------------- MLP v2: swapped operands (A=weights, B=points) ---------
// D: col=lane&15=POINT, row=4g+r = 4 consecutive NEURONS -> one b64 LDS
// write per tile (was 32 b16/layer); h layout [pt][n] unchanged for reads.
__global__ __launch_bounds__(256) void mlp2_kernel(
    const uint32_t* __restrict__ featw, const uint16_t* __restrict__ pW1,
    const uint16_t* __restrict__ pW2, const uint16_t* __restrict__ pW3,
    const float* __restrict__ b1p, const float* __restrict__ b2,
    const float* __restrict__ b3p, const float* __restrict__ xyz,
    const float* __restrict__ scal, const float* __restrict__ rot,
    float* __restrict__ out, float* __restrict__ partial, int N) {
  __shared__ alignas(16) uint16_t h_lds[4 * 16 * 136];  // per-wave, reused
  __shared__ float dd[4][16][12];
  __shared__ float bl[4][3];

  int tid = threadIdx.x, wv = tid >> 6, lane = tid & 63;
  int pt = lane & 15, g = lane >> 4;
  int pbase = blockIdx.x * 64 + wv * 16;
  int p = pbase + pt;
  int pc = min(p, N - 1);
  bool pv = p < N;

  // B-operand layer 1: feats (k = level*2+d), same plane-load as before
  union { uint32_t u[4]; short8 v; } cva;
#pragma unroll
  for (int jj = 0; jj < 4; ++jj)
    cva.u[jj] = featw[(size_t)(g * 4 + jj) * N + pc];
  short8 a1 = cva.v;

  uint16_t* hw = &h_lds[wv * 16 * 136];
  const short8* w1f = (const short8*)pW1;
#pragma unroll
  for (int t = 0; t < 8; ++t) {
    f32x4 c;
    {
      const float4 bb = *(const float4*)&b1p[t * 16 + 4 * g];  // row bias
      c[0] = bb.x; c[1] = bb.y; c[2] = bb.z; c[3] = bb.w;
    }
    c = __builtin_amdgcn_mfma_f32_16x16x32_bf16(w1f[t * 64 + lane], a1, c, 0, 0, 0);
    uint32_t u0 = pack_bf2(fmaxf(c[0], 0.f), fmaxf(c[1], 0.f));
    uint32_t u1 = pack_bf2(fmaxf(c[2], 0.f), fmaxf(c[3], 0.f));
    *(uint2*)&hw[pt * 136 + t * 16 + 4 * g] = make_uint2(u0, u1);
  }

  // layer 2: read all B-frags first, then overwrite same slice (in-wave order)
  short8 a2[4];
#pragma unroll
  for (int s = 0; s < 4; ++s)
    a2[s] = *(const short8*)&hw[pt * 136 + s * 32 + g * 8];
  const short8* w2f = (const short8*)pW2;
#pragma unroll
  for (int t = 0; t < 8; ++t) {
    f32x4 c;
    {
      const float4 bb = *(const float4*)&b2[t * 16 + 4 * g];
      c[0] = bb.x; c[1] = bb.y; c[2] = bb.z; c[3] = bb.w;
    }
#pragma unroll
    for (int s = 0; s < 4; ++s)
      c = __builtin_amdgcn_mfma_f32_16x16x32_bf16(w2f[(t * 4 + s) * 64 + lane], a2[s], c, 0, 0, 0);
    uint32_t u0 = pack_bf2(fmaxf(c[0], 0.f), fmaxf(c[1], 0.f));
    uint32_t u1 = pack_bf2(fmaxf(c[2], 0.f), fmaxf(c[3], 0.f));
    *(uint2*)&hw[pt * 136 + t * 16 + 4 * g] = make_uint2(u0, u1);
  }

  // layer 3: 3 tiles of 16 neurons; lane owns point pt, neurons n0..n0+3
  short8 a3[4];
#pragma unroll
  for (int s = 0; s < 4; ++s)
    a3[s] = *(const short8*)&hw[pt * 136 + s * 32 + g * 8];
  const short8* w3f = (const short8*)pW3;
#pragma unroll
  for (int t = 0; t < 3; ++t) {
    f32x4 c;
    {
      const float4 bb = *(const float4*)&b3p[t * 16 + 4 * g];
      c[0] = bb.x; c[1] = bb.y; c[2] = bb.z; c[3] = bb.w;
    }
#pragma unroll
    for (int s = 0; s < 4; ++s)
      c = __builtin_amdgcn_mfma_f32_16x16x32_bf16(w3f[(t * 4 + s) * 64 + lane], a3[s], c, 0, 0, 0);
    int n0 = t * 16 + 4 * g;
    if (n0 >= 10 && n0 + 3 < 42) {
      if (pv) {  // contiguous cols: two float2 stores (8B-aligned)
        float* ob = &out[(size_t)p * 42 + n0];
        *(float2*)ob = make_float2(c[0], c[1]);
        *(float2*)(ob + 2) = make_float2(c[2], c[3]);
      }
    } else if (n0 < 44) {  // boundary tiles: scalar handling
#pragma unroll
      for (int r = 0; r < 4; ++r) {
        int n = n0 + r;
        if (n < 10) dd[wv][pt][n] = c[r];
        else if (n < 42 && pv) out[(size_t)p * 42 + n] = c[r];
      }
    }
  }
  __syncthreads();  // dd written by lanes of same wave only; barrier for safety

  // epilogue (lanes 0..15 = one point each)
  float lx = 0.f, ls = 0.f, lr = 0.f;
  if (lane < 16) {
    int pp = pbase + lane;
    if (pp < N) {
      float d0 = dd[wv][lane][0], d1 = dd[wv][lane][1], d2 = dd[wv][lane][2];
      float d3 = dd[wv][lane][3], d4 = dd[wv][lane][4], d5 = dd[wv][lane][5];
      float d6 = dd[wv][lane][6], d7 = dd[wv][lane][7], d8 = dd[wv][lane][8];
      float d9 = dd[wv][lane][9];
      size_t ob = (size_t)pp * 42;
      out[ob + 0] = xyz[pp * 3 + 0] + d0;
      out[ob + 1] = xyz[pp * 3 + 1] + d1;
      out[ob + 2] = xyz[pp * 3 + 2] + d2;
      out[ob + 3] = scal[pp * 3 + 0] + d3;
      out[ob + 4] = scal[pp * 3 + 1] + d4;
      out[ob + 5] = scal[pp * 3 + 2] + d5;
      out[ob + 6] = rot[pp * 4 + 0] + d6;
      out[ob + 7] = rot[pp * 4 + 1] + d7;
      out[ob + 8] = rot[pp * 4 + 2] + d8;
      out[ob + 9] = rot[pp * 4 + 3] + d9;
      lx = sqrtf(d0 * d0 + d1 * d1 + d2 * d2);
      ls = fabsf(d3) + fabsf(d4) + fabsf(d5);
      lr = fabsf(d6) + fabsf(d7) + fabsf(d8) + fabsf(d9);
    }
  }
#pragma unroll
  for (int off = 32; off; off >>= 1) {
    lx += __shfl_xor(lx, off);
    ls += __shfl_xor(ls, off);
    lr += __shfl_xor(lr, off);
  }
  if (lane == 0) { bl[wv][0] = lx; bl[wv][1] = ls; bl[wv][2] = lr; }
  __syncthreads();
  if (tid == 0) {
    partial[(size_t)blockIdx.x * 3 + 0] = bl[0][0] + bl[1][0] + bl[2][0] + bl[3][0];
    partial[(size_t)blockIdx.x * 3 + 1] = bl[0][1] + bl[1][1] + bl[2][1] + bl[3][1];
    partial[(size_t)blockIdx.x * 3 + 2] = bl[0][2] + bl[1][2] + bl[2][2] + bl[3][2];
  }
}

// ---------------- finalize: losses row N ---------------------------------
__global__ void finalize_kernel(const float* __restrict__ partial, int nb,
                                float* __restrict__ out, int N) {
  int tid = threadIdx.x, wv = tid >> 6, lane = tid & 63;
  __shared__ float red[4][3];
  float s0 = 0.f, s1 = 0.f, s2 = 0.f;
  for (int i = tid; i < nb; i += 256) {
    s0 += partial[(size_t)i * 3 + 0];
    s1 += partial[(size_t)i * 3 + 1];
    s2 += partial[(size_t)i * 3 + 2];
  }
#pragma unroll
  for (int off = 32; off; off >>= 1) {
    s0 += __shfl_xor(s0, off);
    s1 += __shfl_xor(s1, off);
    s2 += __shfl_xor(s2, off);
  }
  if (lane == 0) { red[wv][0] = s0; red[wv][1] = s1; red[wv][2] = s2; }
  __syncthreads();
  size_t base = (size_t)N * 42;
  if (tid == 0) {
    float t0 = red[0][0] + red[1][0] + red[2][0] + red[3][0];
    float t1 = red[0][1] + red[1][1] + red[2][1] + red[3][1];
    float t2 = red[0][2] + red[1][2] + red[2][2] + red[3][2];
    out[base + 0] = t0 / (float)N;
    out[base + 1] = t1 / (float)N;
    out[base + 2] = t2 / (float)N;
  }
  if (tid >= 3 && tid < 42) out[base + tid] = 0.f;
}

extern "C" void kernel_launch(void* const* d_in, const int* in_sizes, int n_in,
                              void* d_out, int out_size, void* d_ws,
                              size_t ws_size, hipStream_t stream) {
  const float* xyz = (const float*)d_in[0];
  const float* scal = (const float*)d_in[1];
  const float* rot = (const float*)d_in[2];
  const float* cond = (const float*)d_in[3];
  const float* table = (const float*)d_in[4];
  const float* amin = (const float*)d_in[5];
  const float* amax = (const float*)d_in[6];
  const float* W1 = (const float*)d_in[7];
  const float* b1 = (const float*)d_in[8];
  const float* W2 = (const float*)d_in[9];
  const float* b2 = (const float*)d_in[10];
  const float* W3 = (const float*)d_in[11];
  const float* b3 = (const float*)d_in[12];
  float* out = (float*)d_out;

  int N = in_sizes[0] / 3;
  int T = in_sizes[4] / (16 * 2);
  int nb = (N + 63) / 64;

  ResArr ra;
  double growth = std::pow(2048.0 / 16.0, 1.0 / 15.0);
  for (int l = 0; l < 16; ++l)
    ra.r[l] = (float)std::floor(16.0 * std::pow(growth, (double)l));

  DOff doffs;
  int doff = 0;
  int dmaxn = 0;
  for (int l = 0; l < 6; ++l) {
    doffs.off[l] = doff;
    int r = (int)ra.r[l];
    int n = (r + 1) * r * (r + 1);
    if (n > dmaxn) dmaxn = n;
    doff += n;
  }

  char* ws = (char*)d_ws;
  size_t off = 0;
  size_t featB = (size_t)16 * (size_t)N * 4;
  uint32_t* featw = (uint32_t*)(ws + off); off += featB;
  uint16_t* pW1 = (uint16_t*)(ws + off); off += 4096 * 2;
  uint16_t* pW2 = (uint16_t*)(ws + off); off += 16384 * 2;
  uint16_t* pW3 = (uint16_t*)(ws + off); off += 6144 * 2;
  float* b1p = (float*)(ws + off); off += 128 * 4;
  float* b3p = (float*)(ws + off); off += 48 * 4;
  float* partial = (float*)(ws + off); off += (size_t)nb * 3 * 4;
  off = (off + 15) & ~(size_t)15;
  uint32_t* tbl8 = (uint32_t*)(ws + off); off += (size_t)10 * (size_t)(T >> 1) * 4;
  uint32_t* dtbl = (uint32_t*)(ws + off); off += (size_t)doff * 4;

  prep_pack_kernel<<<104, 256, 0, stream>>>(W1, W2, W3, pW1, pW2, pW3);
  prep_b1p_kernel<<<1, 192, 0, stream>>>(b1, cond, W1, b3, b1p, b3p);

  int n_i8 = 10 * (T >> 1);
  const float4* t4base = (const float4*)(table + (size_t)6 * (size_t)T * 2);
  tbl_i8_kernel<<<2048, 256, 0, stream>>>(t4base, tbl8, n_i8);
  dense_build_kernel<<<dim3((dmaxn + 255) / 256, 6), 256, 0, stream>>>(
      table, dtbl, doffs, ra, T);

  dim3 hg((N + 255) / 256, 16, 1);
  hash_enc8_kernel<<<hg, 256, 0, stream>>>(xyz, amin, amax, tbl8, dtbl, featw,
                                           N, T, ra, doffs);

  mlp2_kernel<<<nb, 256, 0, stream>>>(featw, pW1, pW2, pW3, b1p, b2, b3p,
                                      xyz, scal, rot, out, partial, N);
  finalize_kernel<<<1, 256, 0, stream>>>(partial, nb, out, N);
}

// Round 11
// 253.566 us; speedup vs baseline: 1.3028x; 1.0710x over previous
//
#include <hip/hip_runtime.h>
#include <stdint.h>
#include <cmath>

typedef short short8 __attribute__((ext_vector_type(8)));
typedef float f32x4 __attribute__((ext_vector_type(4)));

struct ResArr { float r[16]; };
struct DOff { int off[6]; };

__device__ __forceinline__ uint16_t f2bf(float f) {
  uint32_t u;
  __builtin_memcpy(&u, &f, 4);
  uint32_t r = (u + 0x7FFFu + ((u >> 16) & 1u)) >> 16;  // RNE
  return (uint16_t)r;
}

__device__ __forceinline__ uint32_t enc8(float v) {
  int q = __float2int_rn(v * 2048.0f);
  q = max(-127, min(127, q));
  return (uint32_t)(q & 0xFF);
}

// ---------------- prep: f32 table -> int8 pairs, hashed levels 6..15 -----
__global__ __launch_bounds__(256) void tbl_i8_kernel(
    const float4* __restrict__ t4, uint32_t* __restrict__ o, int n) {
  int i = blockIdx.x * 256 + threadIdx.x;
  int stride = gridDim.x * 256;
  for (; i < n; i += stride) {
    float4 v = t4[i];
    o[i] = enc8(v.x) | (enc8(v.y) << 8) | (enc8(v.z) << 16) | (enc8(v.w) << 24);
  }
}

// ---------------- prep: dense [x][z][y] tables for levels 0..5 -----------
__global__ __launch_bounds__(256) void dense_build_kernel(
    const float* __restrict__ tablef, uint32_t* __restrict__ dt,
    DOff doffs, ResArr ra, int T) {
  int lvl = blockIdx.y;  // 0..5
  int r = (int)ra.r[lvl];
  int rp = r + 1;
  int n = rp * r * rp;  // x * z * y
  uint32_t mask = (uint32_t)(T - 1);
  const float* tb = tablef + (size_t)lvl * (size_t)T * 2;
  uint32_t* out = dt + doffs.off[lvl];
  for (int i = blockIdx.x * 256 + threadIdx.x; i < n; i += gridDim.x * 256) {
    int y = i % rp;
    int t = i / rp;
    int z = t % r;
    int x = t / r;
    uint32_t hxy = (uint32_t)x ^ (uint32_t)y * 2654435761u;
    uint32_t h0 = (hxy ^ (uint32_t)z * 805459861u) & mask;
    uint32_t h1 = (hxy ^ (uint32_t)(z + 1) * 805459861u) & mask;
    float a0 = tb[h0 * 2], a1 = tb[h0 * 2 + 1];
    float c0 = tb[h1 * 2], c1 = tb[h1 * 2 + 1];
    out[i] = enc8(a0) | (enc8(a1) << 8) | (enc8(c0) << 16) | (enc8(c1) << 24);
  }
}

// ---------------- prep: pack weights into MFMA B-fragment order (bf16) ----
// pW1/pW2/pW3 are ADJACENT in ws: one 26624-short region staged to LDS.
__global__ __launch_bounds__(256) void prep_pack_kernel(
    const float* __restrict__ W1, const float* __restrict__ W2,
    const float* __restrict__ W3, uint16_t* __restrict__ pW1,
    uint16_t* __restrict__ pW2, uint16_t* __restrict__ pW3) {
  int i = blockIdx.x * 256 + threadIdx.x;
  if (i < 4096) {
    int j = i & 7, lane = (i >> 3) & 63, t = i >> 9;
    int k = (lane >> 4) * 8 + j, col = t * 16 + (lane & 15);
    pW1[i] = f2bf(W1[k * 128 + col]);
  } else if (i < 20480) {
    int q = i - 4096;
    int j = q & 7, lane = (q >> 3) & 63, st = q >> 9;
    int s = st & 3, t = st >> 2;
    int k = s * 32 + (lane >> 4) * 8 + j, col = t * 16 + (lane & 15);
    pW2[q] = f2bf(W2[k * 128 + col]);
  } else if (i < 26624) {
    int q = i - 20480;
    int j = q & 7, lane = (q >> 3) & 63, st = q >> 9;
    int s = st & 3, t = st >> 2;
    int k = s * 32 + (lane >> 4) * 8 + j, col = t * 16 + (lane & 15);
    pW3[q] = (col < 42) ? f2bf(W3[k * 42 + col]) : (uint16_t)0;
  }
}

// b1' = b1 + cond @ W1[32:160]
__global__ void prep_b1p_kernel(const float* __restrict__ b1,
                                const float* __restrict__ cond,
                                const float* __restrict__ W1,
                                float* __restrict__ b1p) {
  int j = threadIdx.x;  // 128 threads
  float acc = b1[j];
  for (int c = 0; c < 128; ++c) acc += cond[c] * W1[(32 + c) * 128 + j];
  b1p[j] = acc;
}

// ---------------- hash grid encode v8 (unchanged, session-best) ----------
__global__ __launch_bounds__(256) void hash_enc8_kernel(
    const float* __restrict__ xyz, const float* __restrict__ amin,
    const float* __restrict__ amax, const uint32_t* __restrict__ tbl8,
    const uint32_t* __restrict__ dtbl, uint32_t* __restrict__ featw,
    int N, int T, ResArr ra, DOff doffs) {
  int lvl = blockIdx.y;
  int p = blockIdx.x * 256 + threadIdx.x;
  if (p >= N) return;

  float mn0 = amin[0], mn1 = amin[1], mn2 = amin[2];
  float x = (xyz[p * 3 + 0] - mn0) / (amax[0] - mn0);
  float y = (xyz[p * 3 + 1] - mn1) / (amax[1] - mn1);
  float z = (xyz[p * 3 + 2] - mn2) / (amax[2] - mn2);
  const float hi = 1.0f - 1e-6f;
  x = fminf(fmaxf(x, 0.f), hi);
  y = fminf(fmaxf(y, 0.f), hi);
  z = fminf(fmaxf(z, 0.f), hi);

  float res = ra.r[lvl];
  float xs0 = x * res, xs1 = y * res, xs2 = z * res;
  float c0 = floorf(xs0), c1 = floorf(xs1), c2 = floorf(xs2);
  float fr0 = xs0 - c0, fr1 = xs1 - c1, fr2 = xs2 - c2;
  int j0 = (int)c0, j1 = (int)c1, j2 = (int)c2;

  float wy0 = 1.f - fr1, wz0 = 1.f - fr2;
  float acc0 = 0.f, acc1 = 0.f;

  if (lvl < 6) {
    int r = (int)res, rp = r + 1;
    const uint32_t* dtb = dtbl + doffs.off[lvl];
#pragma unroll
    for (int bx = 0; bx < 2; ++bx) {
      int base = ((j0 + bx) * r + j2) * rp + j1;
      uint32_t u0 = dtb[base];
      uint32_t u1 = dtb[base + 1];
      float a0 = (float)((int)(u0 << 24) >> 24);
      float a1 = (float)((int)(u0 << 16) >> 24);
      float a2 = (float)((int)(u0 << 8) >> 24);
      float a3 = (float)((int)u0 >> 24);
      float b0 = (float)((int)(u1 << 24) >> 24);
      float b1v = (float)((int)(u1 << 16) >> 24);
      float b2 = (float)((int)(u1 << 8) >> 24);
      float b3 = (float)((int)u1 >> 24);
      float gy0_0 = a0 + fr2 * (a2 - a0), gy0_1 = a1 + fr2 * (a3 - a1);
      float gy1_0 = b0 + fr2 * (b2 - b0), gy1_1 = b1v + fr2 * (b3 - b1v);
      float h0 = gy0_0 + fr1 * (gy1_0 - gy0_0);
      float h1v = gy0_1 + fr1 * (gy1_1 - gy0_1);
      float wx = bx ? fr0 : (1.f - fr0);
      acc0 += wx * h0;
      acc1 += wx * h1v;
    }
  } else {
    uint32_t j0u = (uint32_t)j0;
    uint32_t mask = (uint32_t)(T - 1);
    const uint32_t* tb = tbl8 + (size_t)(lvl - 6) * (size_t)(T >> 1);
    uint32_t hy0 = (uint32_t)j1 * 2654435761u, hy1 = hy0 + 2654435761u;
    uint32_t hz0 = (uint32_t)j2 * 805459861u, hz1 = hz0 + 805459861u;
    bool odd = (j0u & 1u) != 0u;
#pragma unroll
    for (int c = 0; c < 4; ++c) {
      uint32_t hyz = ((c & 1) ? hy1 : hy0) ^ ((c >> 1) ? hz1 : hz0);
      uint32_t idx0 = (j0u ^ hyz) & mask;
      uint32_t idx1 = ((j0u + 1u) ^ hyz) & mask;
      uint32_t u = tb[idx0 >> 1];
      uint32_t u2 = u;
      if (odd) u2 = tb[idx1 >> 1];
      uint32_t ha = (idx0 & 1u) ? (u >> 16) : (u & 0xFFFFu);
      uint32_t hb = (idx1 & 1u) ? (u2 >> 16) : (u2 & 0xFFFFu);
      float fa0 = (float)((int)(ha << 24) >> 24);
      float fa1 = (float)((int)(ha << 16) >> 24);
      float fb0 = (float)((int)(hb << 24) >> 24);
      float fb1 = (float)((int)(hb << 16) >> 24);
      float g0 = fa0 + fr0 * (fb0 - fa0);
      float g1 = fa1 + fr0 * (fb1 - fa1);
      float wyz = ((c & 1) ? fr1 : wy0) * ((c >> 1) ? fr2 : wz0);
      acc0 += wyz * g0;
      acc1 += wyz * g1;
    }
  }

  const float s = 1.0f / 2048.0f;
  featw[(size_t)lvl * N + p] =
      (uint32_t)f2bf(acc0 * s) | ((uint32_t)f2bf(acc1 * s) << 16);
}

// ---------------- MLP v3: R8 structure + LDS-staged weights, 64 pts/wave -
// Weights (52KB of packed fragments) staged to LDS once per block; each
// wave runs the full 3-layer pipeline for 4 point-groups reading weights
// via ds_read_b128 -> weight VMEM traffic drops 16x (1.63GB -> 102MB).
__global__ __launch_bounds__(256) void mlp3_kernel(
    const uint32_t* __restrict__ featw, const uint16_t* __restrict__ pWall,
    const float* __restrict__ b1p, const float* __restrict__ b2,
    const float* __restrict__ b3, const float* __restrict__ xyz,
    const float* __restrict__ scal, const float* __restrict__ rot,
    float* __restrict__ out, float* __restrict__ partial, int N) {
  __shared__ alignas(16) uint16_t wlds[26624];       // 52KB weight frags
  __shared__ alignas(16) uint16_t h_lds[4 * 16 * 136];  // per-wave h (reused)
  __shared__ float dd[4][16][12];
  __shared__ float bl[4][3];

  int tid = threadIdx.x, wv = tid >> 6, lane = tid & 63;
  int rowi = lane & 15, g = lane >> 4;

  // cooperative weight stage: 26624 shorts = 3328 x 16B
  for (int i = tid; i < 3328; i += 256)
    ((uint4*)wlds)[i] = ((const uint4*)pWall)[i];
  __syncthreads();

  const short8* w1f = (const short8*)wlds;
  const short8* w2f = (const short8*)(wlds + 4096);
  const short8* w3f = (const short8*)(wlds + 20480);
  uint16_t* hw = &h_lds[wv * 16 * 136];

  float lxs = 0.f, lss = 0.f, lrs = 0.f;  // per-lane loss partials across pgs

  for (int pg = 0; pg < 4; ++pg) {
    int pbase = blockIdx.x * 256 + wv * 64 + pg * 16;
    int prow = pbase + rowi;
    int pc = min(prow, N - 1);

    // ---- layer 1: A = feats (global plane loads)
    union { uint32_t u[4]; short8 v; } cva;
#pragma unroll
    for (int jj = 0; jj < 4; ++jj)
      cva.u[jj] = featw[(size_t)(g * 4 + jj) * N + pc];
    short8 a1 = cva.v;

#pragma unroll
    for (int t = 0; t < 8; ++t) {
      float bb = b1p[t * 16 + rowi];
      f32x4 c = {bb, bb, bb, bb};
      c = __builtin_amdgcn_mfma_f32_16x16x32_bf16(a1, w1f[t * 64 + lane], c, 0, 0, 0);
#pragma unroll
      for (int r = 0; r < 4; ++r)
        hw[(4 * g + r) * 136 + t * 16 + rowi] = f2bf(fmaxf(c[r], 0.f));
    }

    // ---- layer 2 (read-all-then-write, in-wave DS order => safe)
    short8 a2[4];
#pragma unroll
    for (int s = 0; s < 4; ++s)
      a2[s] = *(const short8*)&hw[rowi * 136 + s * 32 + g * 8];
#pragma unroll
    for (int t = 0; t < 8; ++t) {
      float bb = b2[t * 16 + rowi];
      f32x4 c = {bb, bb, bb, bb};
#pragma unroll
      for (int s = 0; s < 4; ++s)
        c = __builtin_amdgcn_mfma_f32_16x16x32_bf16(a2[s], w2f[(t * 4 + s) * 64 + lane], c, 0, 0, 0);
#pragma unroll
      for (int r = 0; r < 4; ++r)
        hw[(4 * g + r) * 136 + t * 16 + rowi] = f2bf(fmaxf(c[r], 0.f));
    }

    // ---- layer 3
    short8 a3[4];
#pragma unroll
    for (int s = 0; s < 4; ++s)
      a3[s] = *(const short8*)&hw[rowi * 136 + s * 32 + g * 8];
#pragma unroll
    for (int t = 0; t < 3; ++t) {
      int col = t * 16 + rowi;
      float bb = (col < 42) ? b3[col] : 0.f;
      f32x4 c = {bb, bb, bb, bb};
#pragma unroll
      for (int s = 0; s < 4; ++s)
        c = __builtin_amdgcn_mfma_f32_16x16x32_bf16(a3[s], w3f[(t * 4 + s) * 64 + lane], c, 0, 0, 0);
      if (col >= 10 && col < 42) {
#pragma unroll
        for (int r = 0; r < 4; ++r) {
          int p = pbase + 4 * g + r;
          if (p < N) out[(size_t)p * 42 + col] = c[r];
        }
      } else if (col < 10) {
#pragma unroll
        for (int r = 0; r < 4; ++r) dd[wv][4 * g + r][col] = c[r];
      }
    }

    // ---- epilogue (dd per-wave; in-wave DS ordering, no barrier needed)
    float lx = 0.f, ls = 0.f, lr = 0.f;
    if (lane < 16) {
      int p = pbase + lane;
      if (p < N) {
        float d0 = dd[wv][lane][0], d1 = dd[wv][lane][1], d2 = dd[wv][lane][2];
        float d3 = dd[wv][lane][3], d4 = dd[wv][lane][4], d5 = dd[wv][lane][5];
        float d6 = dd[wv][lane][6], d7 = dd[wv][lane][7], d8 = dd[wv][lane][8];
        float d9 = dd[wv][lane][9];
        size_t ob = (size_t)p * 42;
        out[ob + 0] = xyz[p * 3 + 0] + d0;
        out[ob + 1] = xyz[p * 3 + 1] + d1;
        out[ob + 2] = xyz[p * 3 + 2] + d2;
        out[ob + 3] = scal[p * 3 + 0] + d3;
        out[ob + 4] = scal[p * 3 + 1] + d4;
        out[ob + 5] = scal[p * 3 + 2] + d5;
        out[ob + 6] = rot[p * 4 + 0] + d6;
        out[ob + 7] = rot[p * 4 + 1] + d7;
        out[ob + 8] = rot[p * 4 + 2] + d8;
        out[ob + 9] = rot[p * 4 + 3] + d9;
        lx = sqrtf(d0 * d0 + d1 * d1 + d2 * d2);
        ls = fabsf(d3) + fabsf(d4) + fabsf(d5);
        lr = fabsf(d6) + fabsf(d7) + fabsf(d8) + fabsf(d9);
      }
    }
    lxs += lx;
    lss += ls;
    lrs += lr;
  }

#pragma unroll
  for (int off = 32; off; off >>= 1) {
    lxs += __shfl_xor(lxs, off);
    lss += __shfl_xor(lss, off);
    lrs += __shfl_xor(lrs, off);
  }
  if (lane == 0) { bl[wv][0] = lxs; bl[wv][1] = lss; bl[wv][2] = lrs; }
  __syncthreads();
  if (tid == 0) {
    partial[(size_t)blockIdx.x * 3 + 0] = bl[0][0] + bl[1][0] + bl[2][0] + bl[3][0];
    partial[(size_t)blockIdx.x * 3 + 1] = bl[0][1] + bl[1][1] + bl[2][1] + bl[3][1];
    partial[(size_t)blockIdx.x * 3 + 2] = bl[0][2] + bl[1][2] + bl[2][2] + bl[3][2];
  }
}

// ---------------- finalize: losses row N ---------------------------------
__global__ void finalize_kernel(const float* __restrict__ partial, int nb,
                                float* __restrict__ out, int N) {
  int tid = threadIdx.x, wv = tid >> 6, lane = tid & 63;
  __shared__ float red[4][3];
  float s0 = 0.f, s1 = 0.f, s2 = 0.f;
  for (int i = tid; i < nb; i += 256) {
    s0 += partial[(size_t)i * 3 + 0];
    s1 += partial[(size_t)i * 3 + 1];
    s2 += partial[(size_t)i * 3 + 2];
  }
#pragma unroll
  for (int off = 32; off; off >>= 1) {
    s0 += __shfl_xor(s0, off);
    s1 += __shfl_xor(s1, off);
    s2 += __shfl_xor(s2, off);
  }
  if (lane == 0) { red[wv][0] = s0; red[wv][1] = s1; red[wv][2] = s2; }
  __syncthreads();
  size_t base = (size_t)N * 42;
  if (tid == 0) {
    float t0 = red[0][0] + red[1][0] + red[2][0] + red[3][0];
    float t1 = red[0][1] + red[1][1] + red[2][1] + red[3][1];
    float t2 = red[0][2] + red[1][2] + red[2][2] + red[3][2];
    out[base + 0] = t0 / (float)N;
    out[base + 1] = t1 / (float)N;
    out[base + 2] = t2 / (float)N;
  }
  if (tid >= 3 && tid < 42) out[base + tid] = 0.f;
}

extern "C" void kernel_launch(void* const* d_in, const int* in_sizes, int n_in,
                              void* d_out, int out_size, void* d_ws,
                              size_t ws_size, hipStream_t stream) {
  const float* xyz = (const float*)d_in[0];
  const float* scal = (const float*)d_in[1];
  const float* rot = (const float*)d_in[2];
  const float* cond = (const float*)d_in[3];
  const float* table = (const float*)d_in[4];
  const float* amin = (const float*)d_in[5];
  const float* amax = (const float*)d_in[6];
  const float* W1 = (const float*)d_in[7];
  const float* b1 = (const float*)d_in[8];
  const float* W2 = (const float*)d_in[9];
  const float* b2 = (const float*)d_in[10];
  const float* W3 = (const float*)d_in[11];
  const float* b3 = (const float*)d_in[12];
  float* out = (float*)d_out;

  int N = in_sizes[0] / 3;
  int T = in_sizes[4] / (16 * 2);
  int nb = (N + 255) / 256;  // mlp3: 256 points per block

  ResArr ra;
  double growth = std::pow(2048.0 / 16.0, 1.0 / 15.0);
  for (int l = 0; l < 16; ++l)
    ra.r[l] = (float)std::floor(16.0 * std::pow(growth, (double)l));

  DOff doffs;
  int doff = 0;
  int dmaxn = 0;
  for (int l = 0; l < 6; ++l) {
    doffs.off[l] = doff;
    int r = (int)ra.r[l];
    int n = (r + 1) * r * (r + 1);
    if (n > dmaxn) dmaxn = n;
    doff += n;
  }

  char* ws = (char*)d_ws;
  size_t off = 0;
  size_t featB = (size_t)16 * (size_t)N * 4;
  uint32_t* featw = (uint32_t*)(ws + off); off += featB;
  uint16_t* pW1 = (uint16_t*)(ws + off); off += 4096 * 2;   // contiguous:
  uint16_t* pW2 = (uint16_t*)(ws + off); off += 16384 * 2;  //   pWall block
  uint16_t* pW3 = (uint16_t*)(ws + off); off += 6144 * 2;
  float* b1p = (float*)(ws + off); off += 128 * 4;
  float* partial = (float*)(ws + off); off += (size_t)nb * 3 * 4;
  off = (off + 15) & ~(size_t)15;
  uint32_t* tbl8 = (uint32_t*)(ws + off); off += (size_t)10 * (size_t)(T >> 1) * 4;
  uint32_t* dtbl = (uint32_t*)(ws + off); off += (size_t)doff * 4;

  prep_pack_kernel<<<104, 256, 0, stream>>>(W1, W2, W3, pW1, pW2, pW3);
  prep_b1p_kernel<<<1, 128, 0, stream>>>(b1, cond, W1, b1p);

  int n_i8 = 10 * (T >> 1);
  const float4* t4base = (const float4*)(table + (size_t)6 * (size_t)T * 2);
  tbl_i8_kernel<<<2048, 256, 0, stream>>>(t4base, tbl8, n_i8);
  dense_build_kernel<<<dim3((dmaxn + 255) / 256, 6), 256, 0, stream>>>(
      table, dtbl, doffs, ra, T);

  dim3 hg((N + 255) / 256, 16, 1);
  hash_enc8_kernel<<<hg, 256, 0, stream>>>(xyz, amin, amax, tbl8, dtbl, featw,
                                           N, T, ra, doffs);

  mlp3_kernel<<<nb, 256, 0, stream>>>(featw, pW1, b1p, b2, b3,
                                      xyz, scal, rot, out, partial, N);
  finalize_kernel<<<1, 256, 0, stream>>>(partial, nb, out, N);
}

// Round 12
// 250.277 us; speedup vs baseline: 1.3199x; 1.0131x over previous
//
#include <hip/hip_runtime.h>
#include <stdint.h>
#include <cmath>

typedef short short8 __attribute__((ext_vector_type(8)));
typedef float f32x4 __attribute__((ext_vector_type(4)));

struct ResArr { float r[16]; };
struct DOff { int off[6]; };

__device__ __forceinline__ uint16_t f2bf(float f) {
  uint32_t u;
  __builtin_memcpy(&u, &f, 4);
  uint32_t r = (u + 0x7FFFu + ((u >> 16) & 1u)) >> 16;  // RNE
  return (uint16_t)r;
}

__device__ __forceinline__ uint32_t enc8(float v) {
  int q = __float2int_rn(v * 2048.0f);
  q = max(-127, min(127, q));
  return (uint32_t)(q & 0xFF);
}

// ---------------- merged prep: tbl_i8 | xyzq | weight-pack | b1p ---------
__global__ __launch_bounds__(256) void prep_misc_kernel(
    const float4* __restrict__ t4, uint32_t* __restrict__ tbl8, int n_i8,
    const float* __restrict__ xyz, const float* __restrict__ amin,
    const float* __restrict__ amax, uint2* __restrict__ xyzq, int N,
    const float* __restrict__ W1, const float* __restrict__ W2,
    const float* __restrict__ W3, uint16_t* __restrict__ pW1,
    uint16_t* __restrict__ pW2, uint16_t* __restrict__ pW3,
    const float* __restrict__ b1, const float* __restrict__ cond,
    float* __restrict__ b1p) {
  int b = blockIdx.x, tid = threadIdx.x;
  if (b < 1536) {
    // int8 pair tables for hashed levels 6..15
    for (int i = b * 256 + tid; i < n_i8; i += 1536 * 256) {
      float4 v = t4[i];
      uint32_t o = enc8(v.x) | (enc8(v.y) << 8) | (enc8(v.z) << 16) |
                   (enc8(v.w) << 24);
      tbl8[i] = o;
    }
  } else if (b < 1792) {
    // xyz -> normalized+clamped, 3x21-bit packed
    float mn0 = amin[0], mn1 = amin[1], mn2 = amin[2];
    float i0 = 1.f / (amax[0] - mn0), i1 = 1.f / (amax[1] - mn1);
    float i2 = 1.f / (amax[2] - mn2);
    const float hi = 1.0f - 1e-6f, S = 2097152.0f;  // 2^21
    for (int p = (b - 1536) * 256 + tid; p < N; p += 256 * 256) {
      float x = fminf(fmaxf((xyz[p * 3 + 0] - mn0) * i0, 0.f), hi);
      float y = fminf(fmaxf((xyz[p * 3 + 1] - mn1) * i1, 0.f), hi);
      float z = fminf(fmaxf((xyz[p * 3 + 2] - mn2) * i2, 0.f), hi);
      uint32_t q0 = (uint32_t)(x * S), q1 = (uint32_t)(y * S),
               q2 = (uint32_t)(z * S);
      uint2 u;
      u.x = q0 | (q1 << 21);
      u.y = (q1 >> 11) | (q2 << 10);
      xyzq[p] = u;
    }
  } else if (b < 1896) {
    int i = (b - 1792) * 256 + tid;  // 0..26623
    if (i < 4096) {
      int j = i & 7, lane = (i >> 3) & 63, t = i >> 9;
      int k = (lane >> 4) * 8 + j, col = t * 16 + (lane & 15);
      pW1[i] = f2bf(W1[k * 128 + col]);
    } else if (i < 20480) {
      int q = i - 4096;
      int j = q & 7, lane = (q >> 3) & 63, st = q >> 9;
      int s = st & 3, t = st >> 2;
      int k = s * 32 + (lane >> 4) * 8 + j, col = t * 16 + (lane & 15);
      pW2[q] = f2bf(W2[k * 128 + col]);
    } else {
      int q = i - 20480;
      int j = q & 7, lane = (q >> 3) & 63, st = q >> 9;
      int s = st & 3, t = st >> 2;
      int k = s * 32 + (lane >> 4) * 8 + j, col = t * 16 + (lane & 15);
      pW3[q] = (col < 42) ? f2bf(W3[k * 42 + col]) : (uint16_t)0;
    }
  } else {
    if (tid < 128) {
      float acc = b1[tid];
      for (int c = 0; c < 128; ++c) acc += cond[c] * W1[(32 + c) * 128 + tid];
      b1p[tid] = acc;
    }
  }
}

// ---------------- prep: dense [x][z][y] tables for levels 0..5 -----------
__global__ __launch_bounds__(256) void dense_build_kernel(
    const float* __restrict__ tablef, uint32_t* __restrict__ dt,
    DOff doffs, ResArr ra, int T) {
  int lvl = blockIdx.y;  // 0..5
  int r = (int)ra.r[lvl];
  int rp = r + 1;
  int n = rp * r * rp;  // x * z * y
  uint32_t mask = (uint32_t)(T - 1);
  const float* tb = tablef + (size_t)lvl * (size_t)T * 2;
  uint32_t* out = dt + doffs.off[lvl];
  for (int i = blockIdx.x * 256 + threadIdx.x; i < n; i += gridDim.x * 256) {
    int y = i % rp;
    int t = i / rp;
    int z = t % r;
    int x = t / r;
    uint32_t hxy = (uint32_t)x ^ (uint32_t)y * 2654435761u;
    uint32_t h0 = (hxy ^ (uint32_t)z * 805459861u) & mask;
    uint32_t h1 = (hxy ^ (uint32_t)(z + 1) * 805459861u) & mask;
    float a0 = tb[h0 * 2], a1 = tb[h0 * 2 + 1];
    float c0 = tb[h1 * 2], c1 = tb[h1 * 2 + 1];
    out[i] = enc8(a0) | (enc8(a1) << 8) | (enc8(c0) << 16) | (enc8(c1) << 24);
  }
}

// ---------------- hash grid encode v9: packed xyzq input -----------------
__global__ __launch_bounds__(256) void hash_enc9_kernel(
    const uint2* __restrict__ xyzq, const uint32_t* __restrict__ tbl8,
    const uint32_t* __restrict__ dtbl, uint32_t* __restrict__ featw,
    int N, int T, ResArr ra, DOff doffs) {
  int lvl = blockIdx.y;
  int p = blockIdx.x * 256 + threadIdx.x;
  if (p >= N) return;

  uint2 u = xyzq[p];
  uint32_t q0 = u.x & 0x1FFFFFu;
  uint32_t q1 = ((u.x >> 21) | (u.y << 11)) & 0x1FFFFFu;
  uint32_t q2 = (u.y >> 10) & 0x1FFFFFu;
  const float inv = 4.76837158203125e-7f;  // 2^-21
  float x = (float)q0 * inv, y = (float)q1 * inv, z = (float)q2 * inv;

  float res = ra.r[lvl];
  float xs0 = x * res, xs1 = y * res, xs2 = z * res;
  float c0 = floorf(xs0), c1 = floorf(xs1), c2 = floorf(xs2);
  float fr0 = xs0 - c0, fr1 = xs1 - c1, fr2 = xs2 - c2;
  int j0 = (int)c0, j1 = (int)c1, j2 = (int)c2;

  float wy0 = 1.f - fr1, wz0 = 1.f - fr2;
  float acc0 = 0.f, acc1 = 0.f;

  if (lvl < 6) {
    int r = (int)res, rp = r + 1;
    const uint32_t* dtb = dtbl + doffs.off[lvl];
#pragma unroll
    for (int bx = 0; bx < 2; ++bx) {
      int base = ((j0 + bx) * r + j2) * rp + j1;
      uint32_t u0 = dtb[base];
      uint32_t u1 = dtb[base + 1];
      float a0 = (float)((int)(u0 << 24) >> 24);
      float a1 = (float)((int)(u0 << 16) >> 24);
      float a2 = (float)((int)(u0 << 8) >> 24);
      float a3 = (float)((int)u0 >> 24);
      float b0 = (float)((int)(u1 << 24) >> 24);
      float b1v = (float)((int)(u1 << 16) >> 24);
      float b2 = (float)((int)(u1 << 8) >> 24);
      float b3 = (float)((int)u1 >> 24);
      float gy0_0 = a0 + fr2 * (a2 - a0), gy0_1 = a1 + fr2 * (a3 - a1);
      float gy1_0 = b0 + fr2 * (b2 - b0), gy1_1 = b1v + fr2 * (b3 - b1v);
      float h0 = gy0_0 + fr1 * (gy1_0 - gy0_0);
      float h1v = gy0_1 + fr1 * (gy1_1 - gy0_1);
      float wx = bx ? fr0 : (1.f - fr0);
      acc0 += wx * h0;
      acc1 += wx * h1v;
    }
  } else {
    uint32_t j0u = (uint32_t)j0;
    uint32_t mask = (uint32_t)(T - 1);
    const uint32_t* tb = tbl8 + (size_t)(lvl - 6) * (size_t)(T >> 1);
    uint32_t hy0 = (uint32_t)j1 * 2654435761u, hy1 = hy0 + 2654435761u;
    uint32_t hz0 = (uint32_t)j2 * 805459861u, hz1 = hz0 + 805459861u;
    bool odd = (j0u & 1u) != 0u;
#pragma unroll
    for (int c = 0; c < 4; ++c) {
      uint32_t hyz = ((c & 1) ? hy1 : hy0) ^ ((c >> 1) ? hz1 : hz0);
      uint32_t idx0 = (j0u ^ hyz) & mask;
      uint32_t idx1 = ((j0u + 1u) ^ hyz) & mask;
      uint32_t w = tb[idx0 >> 1];
      uint32_t w2 = w;
      if (odd) w2 = tb[idx1 >> 1];
      uint32_t ha = (idx0 & 1u) ? (w >> 16) : (w & 0xFFFFu);
      uint32_t hb = (idx1 & 1u) ? (w2 >> 16) : (w2 & 0xFFFFu);
      float fa0 = (float)((int)(ha << 24) >> 24);
      float fa1 = (float)((int)(ha << 16) >> 24);
      float fb0 = (float)((int)(hb << 24) >> 24);
      float fb1 = (float)((int)(hb << 16) >> 24);
      float g0 = fa0 + fr0 * (fb0 - fa0);
      float g1 = fa1 + fr0 * (fb1 - fa1);
      float wyz = ((c & 1) ? fr1 : wy0) * ((c >> 1) ? fr2 : wz0);
      acc0 += wyz * g0;
      acc1 += wyz * g1;
    }
  }

  const float s = 1.0f / 2048.0f;
  featw[(size_t)lvl * N + p] =
      (uint32_t)f2bf(acc0 * s) | ((uint32_t)f2bf(acc1 * s) << 16);
}

// ---------------- MLP v4: LDS weights + LDS row-assembled epilogue -------
// Layer-3 output assembled as f32 rows in LDS (stride 50 to dodge banks);
// inputs added cooperatively; final store = 11 fully-coalesced dword
// stores covering whole 42-col rows (was ~160 stride-168B line touches).
__global__ __launch_bounds__(256) void mlp4_kernel(
    const uint32_t* __restrict__ featw, const uint16_t* __restrict__ pWall,
    const float* __restrict__ b1p, const float* __restrict__ b2,
    const float* __restrict__ b3, const float* __restrict__ xyz,
    const float* __restrict__ scal, const float* __restrict__ rot,
    float* __restrict__ out, float* __restrict__ partial, int N) {
  __shared__ alignas(16) uint16_t wlds[26624];          // 52KB weight frags
  __shared__ alignas(16) uint16_t h_lds[4 * 2176];      // per-wave h / rows
  __shared__ float bl[4][3];

  int tid = threadIdx.x, wv = tid >> 6, lane = tid & 63;
  int rowi = lane & 15, g = lane >> 4;

  for (int i = tid; i < 3328; i += 256)
    ((uint4*)wlds)[i] = ((const uint4*)pWall)[i];
  __syncthreads();

  const short8* w1f = (const short8*)wlds;
  const short8* w2f = (const short8*)(wlds + 4096);
  const short8* w3f = (const short8*)(wlds + 20480);
  uint16_t* hw = &h_lds[wv * 2176];
  float* h3f = (float*)hw;  // 16 rows x stride 50 floats (3200B < 4352B)

  float lxs = 0.f, lss = 0.f, lrs = 0.f;

  for (int pg = 0; pg < 4; ++pg) {
    int pbase = blockIdx.x * 256 + wv * 64 + pg * 16;
    int prow = pbase + rowi;
    int pc = min(prow, N - 1);

    // ---- layer 1
    union { uint32_t u[4]; short8 v; } cva;
#pragma unroll
    for (int jj = 0; jj < 4; ++jj)
      cva.u[jj] = featw[(size_t)(g * 4 + jj) * N + pc];
    short8 a1 = cva.v;

#pragma unroll
    for (int t = 0; t < 8; ++t) {
      float bb = b1p[t * 16 + rowi];
      f32x4 c = {bb, bb, bb, bb};
      c = __builtin_amdgcn_mfma_f32_16x16x32_bf16(a1, w1f[t * 64 + lane], c, 0, 0, 0);
#pragma unroll
      for (int r = 0; r < 4; ++r)
        hw[(4 * g + r) * 136 + t * 16 + rowi] = f2bf(fmaxf(c[r], 0.f));
    }

    // ---- layer 2
    short8 a2[4];
#pragma unroll
    for (int s = 0; s < 4; ++s)
      a2[s] = *(const short8*)&hw[rowi * 136 + s * 32 + g * 8];
#pragma unroll
    for (int t = 0; t < 8; ++t) {
      float bb = b2[t * 16 + rowi];
      f32x4 c = {bb, bb, bb, bb};
#pragma unroll
      for (int s = 0; s < 4; ++s)
        c = __builtin_amdgcn_mfma_f32_16x16x32_bf16(a2[s], w2f[(t * 4 + s) * 64 + lane], c, 0, 0, 0);
#pragma unroll
      for (int r = 0; r < 4; ++r)
        hw[(4 * g + r) * 136 + t * 16 + rowi] = f2bf(fmaxf(c[r], 0.f));
    }

    // ---- layer 3 -> f32 rows in LDS (reads of hw precede writes, in-wave)
    short8 a3[4];
#pragma unroll
    for (int s = 0; s < 4; ++s)
      a3[s] = *(const short8*)&hw[rowi * 136 + s * 32 + g * 8];
#pragma unroll
    for (int t = 0; t < 3; ++t) {
      int col = t * 16 + rowi;
      float bb = (col < 42) ? b3[col] : 0.f;
      f32x4 c = {bb, bb, bb, bb};
#pragma unroll
      for (int s = 0; s < 4; ++s)
        c = __builtin_amdgcn_mfma_f32_16x16x32_bf16(a3[s], w3f[(t * 4 + s) * 64 + lane], c, 0, 0, 0);
#pragma unroll
      for (int r = 0; r < 4; ++r)
        h3f[(4 * g + r) * 50 + col] = c[r];
    }

    // ---- loss partials from raw deltas (before input add)
    int vp = N - pbase;  // valid points this group (may be <=0)
    if (lane < 16 && lane < vp) {
      float d0 = h3f[lane * 50 + 0], d1 = h3f[lane * 50 + 1];
      float d2 = h3f[lane * 50 + 2], d3 = h3f[lane * 50 + 3];
      float d4 = h3f[lane * 50 + 4], d5 = h3f[lane * 50 + 5];
      float d6 = h3f[lane * 50 + 6], d7 = h3f[lane * 50 + 7];
      float d8 = h3f[lane * 50 + 8], d9 = h3f[lane * 50 + 9];
      lxs += sqrtf(d0 * d0 + d1 * d1 + d2 * d2);
      lss += fabsf(d3) + fabsf(d4) + fabsf(d5);
      lrs += fabsf(d6) + fabsf(d7) + fabsf(d8) + fabsf(d9);
    }

    // ---- add inputs (coalesced loads; all in-wave LDS ordering)
    int pt3 = (lane * 21846) >> 16;  // lane/3 for lane<48
    int c3 = lane - 3 * pt3;
    int nx = min(48, vp * 3);
    if (lane < nx) {
      float v = xyz[(size_t)pbase * 3 + lane];
      h3f[pt3 * 50 + c3] += v;
      float w = scal[(size_t)pbase * 3 + lane];
      h3f[pt3 * 50 + 3 + c3] += w;
    }
    int nr = min(64, vp * 4);
    if (lane < nr) {
      float v = rot[(size_t)pbase * 4 + lane];
      h3f[(lane >> 2) * 50 + 6 + (lane & 3)] += v;
    }

    // ---- coalesced row store: 16 pts x 42 cols = 672 dwords
#pragma unroll
    for (int q = 0; q < 11; ++q) {
      int idx = lane + q * 64;
      if (idx < 672) {
        int pt = (idx * 1561) >> 16;  // idx/42 (valid for idx<672)
        int col = idx - 42 * pt;
        if (pt < vp)
          out[(size_t)pbase * 42 + idx] = h3f[pt * 50 + col];
      }
    }
  }

#pragma unroll
  for (int off = 32; off; off >>= 1) {
    lxs += __shfl_xor(lxs, off);
    lss += __shfl_xor(lss, off);
    lrs += __shfl_xor(lrs, off);
  }
  if (lane == 0) { bl[wv][0] = lxs; bl[wv][1] = lss; bl[wv][2] = lrs; }
  __syncthreads();
  if (tid == 0) {
    partial[(size_t)blockIdx.x * 3 + 0] = bl[0][0] + bl[1][0] + bl[2][0] + bl[3][0];
    partial[(size_t)blockIdx.x * 3 + 1] = bl[0][1] + bl[1][1] + bl[2][1] + bl[3][1];
    partial[(size_t)blockIdx.x * 3 + 2] = bl[0][2] + bl[1][2] + bl[2][2] + bl[3][2];
  }
}

// ---------------- finalize: losses row N ---------------------------------
__global__ void finalize_kernel(const float* __restrict__ partial, int nb,
                                float* __restrict__ out, int N) {
  int tid = threadIdx.x, wv = tid >> 6, lane = tid & 63;
  __shared__ float red[4][3];
  float s0 = 0.f, s1 = 0.f, s2 = 0.f;
  for (int i = tid; i < nb; i += 256) {
    s0 += partial[(size_t)i * 3 + 0];
    s1 += partial[(size_t)i * 3 + 1];
    s2 += partial[(size_t)i * 3 + 2];
  }
#pragma unroll
  for (int off = 32; off; off >>= 1) {
    s0 += __shfl_xor(s0, off);
    s1 += __shfl_xor(s1, off);
    s2 += __shfl_xor(s2, off);
  }
  if (lane == 0) { red[wv][0] = s0; red[wv][1] = s1; red[wv][2] = s2; }
  __syncthreads();
  size_t base = (size_t)N * 42;
  if (tid == 0) {
    float t0 = red[0][0] + red[1][0] + red[2][0] + red[3][0];
    float t1 = red[0][1] + red[1][1] + red[2][1] + red[3][1];
    float t2 = red[0][2] + red[1][2] + red[2][2] + red[3][2];
    out[base + 0] = t0 / (float)N;
    out[base + 1] = t1 / (float)N;
    out[base + 2] = t2 / (float)N;
  }
  if (tid >= 3 && tid < 42) out[base + tid] = 0.f;
}

extern "C" void kernel_launch(void* const* d_in, const int* in_sizes, int n_in,
                              void* d_out, int out_size, void* d_ws,
                              size_t ws_size, hipStream_t stream) {
  const float* xyz = (const float*)d_in[0];
  const float* scal = (const float*)d_in[1];
  const float* rot = (const float*)d_in[2];
  const float* cond = (const float*)d_in[3];
  const float* table = (const float*)d_in[4];
  const float* amin = (const float*)d_in[5];
  const float* amax = (const float*)d_in[6];
  const float* W1 = (const float*)d_in[7];
  const float* b1 = (const float*)d_in[8];
  const float* W2 = (const float*)d_in[9];
  const float* b2 = (const float*)d_in[10];
  const float* W3 = (const float*)d_in[11];
  const float* b3 = (const float*)d_in[12];
  float* out = (float*)d_out;

  int N = in_sizes[0] / 3;
  int T = in_sizes[4] / (16 * 2);
  int nb = (N + 255) / 256;  // mlp4: 256 points per block

  ResArr ra;
  double growth = std::pow(2048.0 / 16.0, 1.0 / 15.0);
  for (int l = 0; l < 16; ++l)
    ra.r[l] = (float)std::floor(16.0 * std::pow(growth, (double)l));

  DOff doffs;
  int doff = 0;
  int dmaxn = 0;
  for (int l = 0; l < 6; ++l) {
    doffs.off[l] = doff;
    int r = (int)ra.r[l];
    int n = (r + 1) * r * (r + 1);
    if (n > dmaxn) dmaxn = n;
    doff += n;
  }

  char* ws = (char*)d_ws;
  size_t off = 0;
  size_t featB = (size_t)16 * (size_t)N * 4;
  uint32_t* featw = (uint32_t*)(ws + off); off += featB;
  uint16_t* pW1 = (uint16_t*)(ws + off); off += 4096 * 2;   // contiguous pWall
  uint16_t* pW2 = (uint16_t*)(ws + off); off += 16384 * 2;
  uint16_t* pW3 = (uint16_t*)(ws + off); off += 6144 * 2;
  float* b1p = (float*)(ws + off); off += 128 * 4;
  float* partial = (float*)(ws + off); off += (size_t)nb * 3 * 4;
  off = (off + 15) & ~(size_t)15;
  uint2* xyzq = (uint2*)(ws + off); off += (size_t)N * 8;
  uint32_t* tbl8 = (uint32_t*)(ws + off); off += (size_t)10 * (size_t)(T >> 1) * 4;
  uint32_t* dtbl = (uint32_t*)(ws + off); off += (size_t)doff * 4;

  int n_i8 = 10 * (T >> 1);
  const float4* t4base = (const float4*)(table + (size_t)6 * (size_t)T * 2);

  prep_misc_kernel<<<1897, 256, 0, stream>>>(
      t4base, tbl8, n_i8, xyz, amin, amax, xyzq, N, W1, W2, W3, pW1, pW2, pW3,
      b1, cond, b1p);
  dense_build_kernel<<<dim3((dmaxn + 255) / 256, 6), 256, 0, stream>>>(
      table, dtbl, doffs, ra, T);

  dim3 hg((N + 255) / 256, 16, 1);
  hash_enc9_kernel<<<hg, 256, 0, stream>>>(xyzq, tbl8, dtbl, featw, N, T, ra,
                                           doffs);

  mlp4_kernel<<<nb, 256, 0, stream>>>(featw, pW1, b1p, b2, b3, xyz, scal, rot,
                                      out, partial, N);
  finalize_kernel<<<1, 256, 0, stream>>>(partial, nb, out, N);
}